// Round 7
// baseline (598.085 us; speedup 1.0000x reference)
//
#include <hip/hip_runtime.h>
#include <math.h>

// Problem constants (b=8, c=512, n=4096, 8 heads x 64)
#define NB 8
#define CDIM 512
#define NSEQ 4096
#define NHEAD 8
#define DHEAD 64
#define SCALE_Q 0.125f
#define SQRT_C  22.627416997969522f

typedef unsigned short u16;
typedef short bf16x8 __attribute__((ext_vector_type(8)));   // 8 bf16 = 4 VGPR
typedef float f32x4 __attribute__((ext_vector_type(4)));

// ---------------------------------------------------------------------------
// bf16 split helpers (round-to-nearest-even)
// ---------------------------------------------------------------------------
__device__ __forceinline__ u16 f2bf(float f) {
    unsigned u = __float_as_uint(f);
    u = u + 0x7FFFu + ((u >> 16) & 1u);
    return (u16)(u >> 16);
}
__device__ __forceinline__ float bf2f(u16 h) {
    return __uint_as_float(((unsigned)h) << 16);
}
__device__ __forceinline__ void split_bf(float v, u16& h, u16& l) {
    h = f2bf(v);
    l = f2bf(v - bf2f(h));
}

__device__ __forceinline__ void gload_lds16(const void* g, void* l) {
    __builtin_amdgcn_global_load_lds(
        (const __attribute__((address_space(1))) void*)g,
        (__attribute__((address_space(3))) void*)l, 16, 0, 0);
}

// ---------------------------------------------------------------------------
// Split-bf16 MFMA GEMM (NT): C[M,N] = (Ahi+Alo)[M,K] * (Bhi+Blo)[N,K]^T
// Core loop identical to the round-5 kernel (measured 683 TF effective).
// EPI selects a fused epilogue:
//   0 = plain C store                               (v projection)
//   1 = C store + per-row softmax partials (max,sumexp) over this WAVE's
//       64 cols -> S0/S1[row*64 + blockIdx.x*2 + wc]   (k projection)
//       (two waves per block share rows but cover different 64-col halves —
//        they MUST write distinct slots; round-6 draft had them racing)
//   2 = NO C store; in-register softmax over d (64 rows of this wave,
//       cross-lane over h via shfl_xor 16/32), *SCALE, split-bf16, and
//       direct transposed store p^T[b][n][c] -> P0/P1   (q projection)
//   3 = bias + C store + per-column sum-of-squares partial
//       -> S0[(by*2+wr)][b][n]                      (output projection)
// ---------------------------------------------------------------------------
template<int EPI>
__global__ __launch_bounds__(256)
void gemm_split(const u16* __restrict__ Ahi, const u16* __restrict__ Alo,
                const u16* __restrict__ Bhi, const u16* __restrict__ Blo,
                float* __restrict__ C, const float* __restrict__ bias,
                u16* __restrict__ P0, u16* __restrict__ P1,
                float* __restrict__ S0, float* __restrict__ S1,
                int N, int K,
                long long sA, long long sB, long long sC)
{
    Ahi += (long long)blockIdx.z * sA; Alo += (long long)blockIdx.z * sA;
    Bhi += (long long)blockIdx.z * sB; Blo += (long long)blockIdx.z * sB;
    C   += (long long)blockIdx.z * sC;

    __shared__ __align__(16) char sb[32768];   // A 16KB | B 16KB

    const int tid = threadIdx.x;
    const int w = tid >> 6, lane = tid & 63;
    const int wr = w >> 1, wc = w & 1;
    const int row0 = blockIdx.y * 128, col0 = blockIdx.x * 128;

    // staging: lane writes LDS slot (lane&7) of row (lane>>3) in its chunk
    // (linear, HW-imposed); it must therefore LOAD global octet (slot^row).
    const int rsub = lane >> 3;              // row within an 8-row chunk
    const int jsel = (lane & 7) ^ rsub;      // global octet id (0-3 hi, 4-7 lo)
    const int koff = (jsel & 3) << 3;        // k offset in elements
    const u16* aops = (jsel < 4) ? Ahi : Alo;
    const u16* bops = (jsel < 4) ? Bhi : Blo;

    // fragment read offsets (constant across k-steps)
    const int r = lane & 15, h = lane >> 4;
    const int s_hi = (h ^ (r & 7)) << 4;
    const int s_lo = ((h + 4) ^ (r & 7)) << 4;
    int offA[4][2], offB[4][2];
#pragma unroll
    for (int i = 0; i < 4; ++i) {
        const int ra = (wr * 64 + i * 16 + r) * 128;
        offA[i][0] = ra + s_hi;  offA[i][1] = ra + s_lo;
        const int rb = 16384 + (wc * 64 + i * 16 + r) * 128;
        offB[i][0] = rb + s_hi;  offB[i][1] = rb + s_lo;
    }

    f32x4 acc[4][4];
#pragma unroll
    for (int i = 0; i < 4; ++i)
#pragma unroll
        for (int j = 0; j < 4; ++j) acc[i][j] = (f32x4){0.f, 0.f, 0.f, 0.f};

    for (int k0 = 0; k0 < K; k0 += 32) {
        __syncthreads();   // previous tile's reads complete before overwrite
#pragma unroll
        for (int i = 0; i < 4; ++i) {
            const int t = 4 * w + i;   // 8-row chunk index, 0..15
            gload_lds16(aops + (long long)(row0 + 8 * t + rsub) * K + k0 + koff,
                        sb + t * 1024);
            gload_lds16(bops + (long long)(col0 + 8 * t + rsub) * K + k0 + koff,
                        sb + 16384 + t * 1024);
        }
        __syncthreads();   // drains vmcnt: staged data visible

        bf16x8 ah[4], al[4], bh[4], bl[4];
#pragma unroll
        for (int i = 0; i < 4; ++i) {
            ah[i] = *(const bf16x8*)(sb + offA[i][0]);
            al[i] = *(const bf16x8*)(sb + offA[i][1]);
            bh[i] = *(const bf16x8*)(sb + offB[i][0]);
            bl[i] = *(const bf16x8*)(sb + offB[i][1]);
        }
#pragma unroll
        for (int mi = 0; mi < 4; ++mi)
#pragma unroll
            for (int ni = 0; ni < 4; ++ni) {
                acc[mi][ni] = __builtin_amdgcn_mfma_f32_16x16x32_bf16(ah[mi], bh[ni], acc[mi][ni], 0, 0, 0);
                acc[mi][ni] = __builtin_amdgcn_mfma_f32_16x16x32_bf16(ah[mi], bl[ni], acc[mi][ni], 0, 0, 0);
                acc[mi][ni] = __builtin_amdgcn_mfma_f32_16x16x32_bf16(al[mi], bh[ni], acc[mi][ni], 0, 0, 0);
            }
    }

    // --- epilogues. C/D layout: col=lane&15(r), row=(lane>>4)*4+reg [m89] ---
    const int bx = blockIdx.x, by = blockIdx.y, bz = blockIdx.z;

    if constexpr (EPI == 2) {
        // softmax over d per column n: the wave's 64 rows are exactly one
        // head (by*2+wr). Column fixed <=> (ni, r) fixed; rows live on the 4
        // h-lanes (16 values each). shfl_xor 16/32 flips h-bits only.
#pragma unroll
        for (int ni = 0; ni < 4; ++ni) {
            float cm = -INFINITY;
#pragma unroll
            for (int mi = 0; mi < 4; ++mi)
#pragma unroll
                for (int reg = 0; reg < 4; ++reg)
                    cm = fmaxf(cm, acc[mi][ni][reg]);
            cm = fmaxf(cm, __shfl_xor(cm, 16));
            cm = fmaxf(cm, __shfl_xor(cm, 32));
            float cs = 0.f;
#pragma unroll
            for (int mi = 0; mi < 4; ++mi)
#pragma unroll
                for (int reg = 0; reg < 4; ++reg) {
                    const float e = __expf(acc[mi][ni][reg] - cm);
                    acc[mi][ni][reg] = e;
                    cs += e;
                }
            cs += __shfl_xor(cs, 16);
            cs += __shfl_xor(cs, 32);
            const float inv = SCALE_Q / cs;
            const long long coln = col0 + wc * 64 + ni * 16 + r;
            const long long obase = ((long long)bz * NSEQ + coln) * CDIM
                                    + row0 + wr * 64 + h * 4;
#pragma unroll
            for (int mi = 0; mi < 4; ++mi) {
                u16 hv0, lv0, hv1, lv1, hv2, lv2, hv3, lv3;
                split_bf(acc[mi][ni][0] * inv, hv0, lv0);
                split_bf(acc[mi][ni][1] * inv, hv1, lv1);
                split_bf(acc[mi][ni][2] * inv, hv2, lv2);
                split_bf(acc[mi][ni][3] * inv, hv3, lv3);
                ushort4 hq; hq.x = hv0; hq.y = hv1; hq.z = hv2; hq.w = hv3;
                ushort4 lq; lq.x = lv0; lq.y = lv1; lq.z = lv2; lq.w = lv3;
                *(ushort4*)&P0[obase + mi * 16] = hq;   // 8B aligned
                *(ushort4*)&P1[obase + mi * 16] = lq;
            }
        }
        return;
    }

    if constexpr (EPI == 3) {
        // pre-add bias so the ss-partials see final values
#pragma unroll
        for (int mi = 0; mi < 4; ++mi) {
            const int rowm = row0 + wr * 64 + mi * 16 + h * 4;
#pragma unroll
            for (int reg = 0; reg < 4; ++reg) {
                const float bv = bias[rowm + reg];
#pragma unroll
                for (int ni = 0; ni < 4; ++ni) acc[mi][ni][reg] += bv;
            }
        }
    }

    // C store (EPI 0, 1, 3)
#pragma unroll
    for (int mi = 0; mi < 4; ++mi) {
        const int rowm = row0 + wr * 64 + mi * 16 + h * 4;
#pragma unroll
        for (int ni = 0; ni < 4; ++ni) {
            const int coln = col0 + wc * 64 + ni * 16 + r;
#pragma unroll
            for (int reg = 0; reg < 4; ++reg)
                C[(long long)(rowm + reg) * N + coln] = acc[mi][ni][reg];
        }
    }

    if constexpr (EPI == 1) {
        // per-row max & sumexp partials over THIS WAVE's 64 cols.
        // Row fixed <=> (mi, h, reg) fixed; cols on the 16 r-lanes x 4 ni.
        // Distinct slot per (block, wc): 64 partials per row total.
#pragma unroll
        for (int mi = 0; mi < 4; ++mi)
#pragma unroll
            for (int reg = 0; reg < 4; ++reg) {
                float m = -INFINITY;
#pragma unroll
                for (int ni = 0; ni < 4; ++ni) m = fmaxf(m, acc[mi][ni][reg]);
                m = fmaxf(m, __shfl_xor(m, 1));
                m = fmaxf(m, __shfl_xor(m, 2));
                m = fmaxf(m, __shfl_xor(m, 4));
                m = fmaxf(m, __shfl_xor(m, 8));
                float s = 0.f;
#pragma unroll
                for (int ni = 0; ni < 4; ++ni) s += __expf(acc[mi][ni][reg] - m);
                s += __shfl_xor(s, 1);
                s += __shfl_xor(s, 2);
                s += __shfl_xor(s, 4);
                s += __shfl_xor(s, 8);
                if (r == 0) {
                    const int srow = bz * CDIM + row0 + wr * 64 + mi * 16 + h * 4 + reg;
                    S0[srow * 64 + bx * 2 + wc] = m;
                    S1[srow * 64 + bx * 2 + wc] = s;
                }
            }
    }

    if constexpr (EPI == 3) {
        // per-column sum-of-squares partial over this block's 128 rows:
        // combine the wave's 64 rows via shfl over h; slice = by*2+wr.
        // Each column is written by exactly one wave (wc splits columns).
#pragma unroll
        for (int ni = 0; ni < 4; ++ni) {
            float ss = 0.f;
#pragma unroll
            for (int mi = 0; mi < 4; ++mi)
#pragma unroll
                for (int reg = 0; reg < 4; ++reg)
                    ss += acc[mi][ni][reg] * acc[mi][ni][reg];
            ss += __shfl_xor(ss, 16);
            ss += __shfl_xor(ss, 32);
            if (h == 0) {
                const int coln = col0 + wc * 64 + ni * 16 + r;
                S0[(long long)(by * 2 + wr) * (NB * NSEQ)
                   + (long long)bz * NSEQ + coln] = ss;
            }
        }
    }
}

// ---------------------------------------------------------------------------
// k-stats finalize: combine 64 per-wave partials per row.
// sum(exp(x - m)) = sum_i psum_i * exp(pmax_i - m)
// ---------------------------------------------------------------------------
__global__ __launch_bounds__(256)
void kfin_kernel(const float* __restrict__ pmax, const float* __restrict__ psum,
                 float* __restrict__ kmax, float* __restrict__ kinv)
{
    const int row = blockIdx.x * 256 + threadIdx.x;   // grid 16 -> 4096
    float m = -INFINITY;
#pragma unroll
    for (int i = 0; i < 64; ++i) m = fmaxf(m, pmax[row * 64 + i]);
    float s = 0.f;
#pragma unroll
    for (int i = 0; i < 64; ++i)
        s += psum[row * 64 + i] * __expf(pmax[row * 64 + i] - m);
    kmax[row] = m;
    kinv[row] = 1.0f / s;
}

// ---------------------------------------------------------------------------
// Weight split (Wq|Wk|Wv selected by blockIdx.y): fp32 -> (hi, lo) bf16.
// ---------------------------------------------------------------------------
__global__ __launch_bounds__(256)
void cvt3(const float* __restrict__ Wq, const float* __restrict__ Wk,
          const float* __restrict__ Wv, u16* __restrict__ hi,
          u16* __restrict__ lo)
{
    const float* src = (blockIdx.y == 0) ? Wq : ((blockIdx.y == 1) ? Wk : Wv);
    u16* hd = hi + (long long)blockIdx.y * 262144;
    u16* ld = lo + (long long)blockIdx.y * 262144;
    for (int i = blockIdx.x * 256 + threadIdx.x; i < 262144; i += 16384) {
        u16 h, l; split_bf(src[i], h, l);
        hd[i] = h; ld[i] = l;
    }
}

// ---------------------------------------------------------------------------
// x [b][c][n] fp32 -> xT hi/lo bf16 [b][n][c]  (LDS 64x64 tile transpose)
// ---------------------------------------------------------------------------
__global__ __launch_bounds__(256)
void xpose_split(const float* __restrict__ x, u16* __restrict__ thi,
                 u16* __restrict__ tlo)
{
    __shared__ float t[64][65];
    const int tid = threadIdx.x;
    const int b = blockIdx.z, c0 = blockIdx.y * 64, n0 = blockIdx.x * 64;
    const float* xb = x + ((long long)b * CDIM + c0) * NSEQ + n0;
#pragma unroll
    for (int i = 0; i < 16; ++i) {
        const int f = tid + i * 256;
        t[f >> 6][f & 63] = xb[(long long)(f >> 6) * NSEQ + (f & 63)];
    }
    __syncthreads();
#pragma unroll
    for (int i = 0; i < 8; ++i) {
        const int f = tid + i * 256;
        const int nl = f >> 5, c2 = (f & 31) << 1;
        u16 h0, l0, h1, l1;
        split_bf(t[c2][nl], h0, l0);
        split_bf(t[c2 + 1][nl], h1, l1);
        const long long o = ((long long)b * NSEQ + n0 + nl) * CDIM + c0 + c2;
        ushort2 hv; hv.x = h0; hv.y = h1; *(ushort2*)&thi[o] = hv;
        ushort2 lv; lv.x = l0; lv.y = l1; *(ushort2*)&tlo[o] = lv;
    }
}

// ---------------------------------------------------------------------------
// ctx_part[chunk][b,h,d,e] = sum over 512-col n-chunk of
//   softmax_n(k)[d,n] * v[e,n].   No atomics; reduced by ctx_reduce.
// ---------------------------------------------------------------------------
__global__ __launch_bounds__(256)
void ctx_part_kernel(const float* __restrict__ k, const float* __restrict__ v,
                     const float* __restrict__ kmax, const float* __restrict__ kinv,
                     float* __restrict__ ctx_part)
{
    const int chunk = blockIdx.x;        // 0..7
    const int bh = blockIdx.y;           // 0..63
    const int b = bh >> 3, h = bh & 7;

    __shared__ float kt[64 * 64];
    __shared__ float vt[64 * 64];

    const int tid = threadIdx.x;
    const int td = tid & 15, te = tid >> 4;
    const long long rowbase = (long long)b * CDIM + h * DHEAD;

    float acc[4][4];
#pragma unroll
    for (int i = 0; i < 4; ++i)
#pragma unroll
        for (int j = 0; j < 4; ++j) acc[i][j] = 0.f;

    for (int tile = 0; tile < 8; ++tile) {
        const int n0 = chunk * 512 + tile * 64;
        __syncthreads();
#pragma unroll
        for (int i = 0; i < 4; ++i) {
            const int f = tid + i * 256;
            const int row = f >> 4;
            const int c4 = (f & 15) << 2;
            const int cs = c4 ^ (((row >> 2) & 7) << 2);
            float4 kv = *(const float4*)&k[(rowbase + row) * (long long)NSEQ + n0 + c4];
            const float m_ = kmax[rowbase + row];
            const float s_ = kinv[rowbase + row];
            kv.x = __expf(kv.x - m_) * s_; kv.y = __expf(kv.y - m_) * s_;
            kv.z = __expf(kv.z - m_) * s_; kv.w = __expf(kv.w - m_) * s_;
            *(float4*)&kt[row * 64 + cs] = kv;
            *(float4*)&vt[row * 64 + cs] =
                *(const float4*)&v[(rowbase + row) * (long long)NSEQ + n0 + c4];
        }
        __syncthreads();

#pragma unroll
        for (int nn = 0; nn < 64; nn += 4) {
            float4 ka[4], vb[4];
#pragma unroll
            for (int i = 0; i < 4; ++i) {
                const int d = td * 4 + i;
                ka[i] = *(const float4*)&kt[d * 64 + (nn ^ (((d >> 2) & 7) << 2))];
            }
#pragma unroll
            for (int j = 0; j < 4; ++j) {
                const int e = te * 4 + j;
                vb[j] = *(const float4*)&vt[e * 64 + (nn ^ (((e >> 2) & 7) << 2))];
            }
#pragma unroll
            for (int i = 0; i < 4; ++i)
#pragma unroll
                for (int j = 0; j < 4; ++j) {
                    acc[i][j] = fmaf(ka[i].x, vb[j].x, acc[i][j]);
                    acc[i][j] = fmaf(ka[i].y, vb[j].y, acc[i][j]);
                    acc[i][j] = fmaf(ka[i].z, vb[j].z, acc[i][j]);
                    acc[i][j] = fmaf(ka[i].w, vb[j].w, acc[i][j]);
                }
        }
    }

    float* cbase = ctx_part + (long long)chunk * 262144 + ((long long)bh << 12);
#pragma unroll
    for (int i = 0; i < 4; ++i)
#pragma unroll
        for (int j = 0; j < 4; ++j)
            cbase[(td * 4 + i) * 64 + te * 4 + j] = acc[i][j];
}

__global__ __launch_bounds__(256)
void ctx_reduce(const float* __restrict__ part, float* __restrict__ ctx)
{
    const int i = blockIdx.x * 256 + threadIdx.x;   // grid 1024 -> 262144
    float s = 0.f;
#pragma unroll
    for (int c = 0; c < 8; ++c) s += part[(long long)c * 262144 + i];
    ctx[i] = s;
}

// ---------------------------------------------------------------------------
// W2[b][o][h*64+d] = sum_e Wout[o][h*64+e] * ctx[b][h][d][e] -> split bf16
// ---------------------------------------------------------------------------
__global__ __launch_bounds__(256)
void w2_split(const float* __restrict__ Wout, const float* __restrict__ ctx,
              u16* __restrict__ w2hi, u16* __restrict__ w2lo)
{
    const int o0 = blockIdx.x * 128;
    const int h = blockIdx.y, b = blockIdx.z;
    const int tid = threadIdx.x;

    __shared__ float ctxT[64 * 65];      // [e][d]
    __shared__ float WoutS[128 * 65];    // [o_local][e]

    const float* csrc = ctx + (((long long)b * NHEAD + h) << 12);
#pragma unroll
    for (int i = 0; i < 16; ++i) {
        const int f = tid + i * 256;
        ctxT[(f & 63) * 65 + (f >> 6)] = csrc[f];
    }
#pragma unroll
    for (int i = 0; i < 32; ++i) {
        const int f = tid + i * 256;
        WoutS[(f >> 6) * 65 + (f & 63)] =
            Wout[(long long)(o0 + (f >> 6)) * CDIM + h * DHEAD + (f & 63)];
    }
    __syncthreads();

    const int d = tid & 63, og = tid >> 6;
    float acc[32];
#pragma unroll
    for (int oo = 0; oo < 32; ++oo) acc[oo] = 0.f;

    for (int e = 0; e < 64; ++e) {
        const float c = ctxT[e * 65 + d];
#pragma unroll
        for (int oo = 0; oo < 32; ++oo)
            acc[oo] = fmaf(WoutS[(og * 32 + oo) * 65 + e], c, acc[oo]);
    }
#pragma unroll
    for (int oo = 0; oo < 32; ++oo) {
        const int o = o0 + og * 32 + oo;
        u16 hh, ll; split_bf(acc[oo], hh, ll);
        const long long idx = ((long long)b * CDIM + o) * CDIM + h * DHEAD + d;
        w2hi[idx] = hh; w2lo[idx] = ll;
    }
}

// ---------------------------------------------------------------------------
// RMSNorm pass 2: combine 8 ss-partials per (b,n), scale outpre -> out.
// Single read of outpre (partials computed in the final GEMM's epilogue).
// ---------------------------------------------------------------------------
__global__ __launch_bounds__(256)
void rmsnorm2(const float* __restrict__ pre, const float* __restrict__ ssp,
              const float* __restrict__ g, float* __restrict__ out)
{
    const int b = blockIdx.y;
    const int n4 = (blockIdx.x * 256 + threadIdx.x) * 4;   // grid (4, NB)
    float4 ss = {0.f, 0.f, 0.f, 0.f};
#pragma unroll
    for (int p = 0; p < 8; ++p) {
        const float4 v = *(const float4*)&ssp[((long long)p * NB + b) * NSEQ + n4];
        ss.x += v.x; ss.y += v.y; ss.z += v.z; ss.w += v.w;
    }
    float4 rn;
    rn.x = SQRT_C / fmaxf(sqrtf(ss.x), 1e-12f);
    rn.y = SQRT_C / fmaxf(sqrtf(ss.y), 1e-12f);
    rn.z = SQRT_C / fmaxf(sqrtf(ss.z), 1e-12f);
    rn.w = SQRT_C / fmaxf(sqrtf(ss.w), 1e-12f);

    const long long base = (long long)b * CDIM * NSEQ + n4;
    for (int c = 0; c < CDIM; ++c) {
        float4 v = *(const float4*)&pre[base + (long long)c * NSEQ];
        const float gc = g[c];
        v.x *= rn.x * gc; v.y *= rn.y * gc;
        v.z *= rn.z * gc; v.w *= rn.w * gc;
        *(float4*)&out[base + (long long)c * NSEQ] = v;
    }
}

// ---------------------------------------------------------------------------
// Workspace layout (floats), lifetime-packed, unchanged total (~155 MB):
//   region A [0, QK)      : xT split (2xQK u16)
//   region B [QK, 2QK)    : k -> out_pre (serial reuse)
//   region C [2QK, ...)   : kmax | kinv | ctx | ctxp (overlaid in time by
//                           {pmax,psum} then ctx_part then ssp) | W | W2
//   d_out                 : v -> p^T split -> final output (serial reuse)
// ---------------------------------------------------------------------------
extern "C" void kernel_launch(void* const* d_in, const int* in_sizes, int n_in,
                              void* d_out, int out_size, void* d_ws, size_t ws_size,
                              hipStream_t stream)
{
    const float* x    = (const float*)d_in[0];
    const float* Wq   = (const float*)d_in[1];
    const float* Wk   = (const float*)d_in[2];
    const float* Wv   = (const float*)d_in[3];
    const float* Wout = (const float*)d_in[4];
    const float* bout = (const float*)d_in[5];
    const float* g    = (const float*)d_in[6];
    float* out = (float*)d_out;

    const long long PB = (long long)CDIM * NSEQ;     // 2,097,152
    const long long QK = (long long)NB * PB;         // 16,777,216

    const long long C_FLOATS = 8192 + 9LL * 262144 + 11LL * 262144;
    const size_t WS_NEEDED = (size_t)(2 * QK + C_FLOATS) * sizeof(float);
    if (ws_size < WS_NEEDED) return;   // constant across calls: capture-safe

    float* ws = (float*)d_ws;
    u16* xthi = (u16*)ws;                  // region A: QK u16
    u16* xtlo = xthi + QK;                 //           QK u16
    float* buf1 = ws + QK;                 // region B: QK floats
    float* kmax = ws + 2 * QK;             // region C
    float* kinv = kmax + 4096;
    float* ctx  = kinv + 4096;             // 262144
    float* ctxp = ctx + 262144;            // 8 x 262144 (time-shared)
    u16* whi    = (u16*)(ctxp + 8 * 262144);   // 3 x 262144 u16
    u16* wlo    = whi + 3 * 262144;
    u16* w2hi   = wlo + 3 * 262144;        // 8 x 262144 u16
    u16* w2lo   = w2hi + (long long)NB * 262144;

    // time-shared overlays of ctxp (disjoint lifetimes):
    float* pmax = ctxp;                    // 262144   (kGEMM -> kfin)
    float* psum = ctxp + 262144;           // 262144
    float* ssp  = ctxp;                    // 262144   (fGEMM -> rmsnorm2)

    float* kbuf = buf1;                    // k until ctx done
    float* outpre = buf1;                  // then final GEMM output
    float* vbuf = out;                     // d_out: v until ctx done
    u16* phi = (u16*)out;                  // then p^T split (2xQK u16 = QK f32)
    u16* plo = phi + QK;

    // weight + input splits
    cvt3<<<dim3(64, 3), 256, 0, stream>>>(Wq, Wk, Wv, whi, wlo);
    xpose_split<<<dim3(64, 8, 8), 256, 0, stream>>>(x, xthi, xtlo);

    const dim3 gg(NSEQ / 128, CDIM / 128, NB);   // (32, 4, 8)

    // k projection + fused softmax-stat partials
    gemm_split<1><<<gg, 256, 0, stream>>>(whi + 262144, wlo + 262144,
                                          xthi, xtlo, kbuf, nullptr,
                                          nullptr, nullptr, pmax, psum,
                                          NSEQ, CDIM, 0, PB, PB);
    kfin_kernel<<<dim3(16), 256, 0, stream>>>(pmax, psum, kmax, kinv);

    // v projection, then context accumulation
    gemm_split<0><<<gg, 256, 0, stream>>>(whi + 2 * 262144, wlo + 2 * 262144,
                                          xthi, xtlo, vbuf, nullptr,
                                          nullptr, nullptr, nullptr, nullptr,
                                          NSEQ, CDIM, 0, PB, PB);
    ctx_part_kernel<<<dim3(8, NB * NHEAD), 256, 0, stream>>>(kbuf, vbuf, kmax, kinv, ctxp);
    ctx_reduce<<<1024, 256, 0, stream>>>(ctxp, ctx);

    // q projection with fused softmax -> p^T (written into d_out; v is dead)
    gemm_split<2><<<gg, 256, 0, stream>>>(whi, wlo,
                                          xthi, xtlo, buf1, nullptr,
                                          phi, plo, nullptr, nullptr,
                                          NSEQ, CDIM, 0, PB, PB);

    // fold ctx into output weights, output projection + bias + ss-partials
    w2_split<<<dim3(4, NHEAD, NB), 256, 0, stream>>>(Wout, ctx, w2hi, w2lo);
    gemm_split<3><<<gg, 256, 0, stream>>>(w2hi, w2lo, phi, plo, outpre, bout,
                                          nullptr, nullptr, ssp, nullptr,
                                          NSEQ, CDIM, 262144, PB, PB);

    // RMSNorm epilogue (single outpre read)
    rmsnorm2<<<dim3(4, NB), 256, 0, stream>>>(outpre, ssp, g, out);
}

// Round 8
// 469.379 us; speedup vs baseline: 1.2742x; 1.2742x over previous
//
#include <hip/hip_runtime.h>
#include <math.h>

// Problem constants (b=8, c=512, n=4096, 8 heads x 64)
#define NB 8
#define CDIM 512
#define NSEQ 4096
#define NHEAD 8
#define DHEAD 64
#define SCALE_Q 0.125f
#define SQRT_C  22.627416997969522f

typedef unsigned short u16;
typedef short bf16x8 __attribute__((ext_vector_type(8)));   // 8 bf16 = 4 VGPR
typedef float f32x4 __attribute__((ext_vector_type(4)));

// ---------------------------------------------------------------------------
// bf16 split helpers (round-to-nearest-even)
// ---------------------------------------------------------------------------
__device__ __forceinline__ u16 f2bf(float f) {
    unsigned u = __float_as_uint(f);
    u = u + 0x7FFFu + ((u >> 16) & 1u);
    return (u16)(u >> 16);
}
__device__ __forceinline__ float bf2f(u16 h) {
    return __uint_as_float(((unsigned)h) << 16);
}
__device__ __forceinline__ void split_bf(float v, u16& h, u16& l) {
    h = f2bf(v);
    l = f2bf(v - bf2f(h));
}

__device__ __forceinline__ void gload_lds16(const void* g, void* l) {
    __builtin_amdgcn_global_load_lds(
        (const __attribute__((address_space(1))) void*)g,
        (__attribute__((address_space(3))) void*)l, 16, 0, 0);
}

// ---------------------------------------------------------------------------
// Split-bf16 MFMA GEMM (NT): C[M,N] = (Ahi+Alo)[M,K] * (Bhi+Blo)[N,K]^T
// Core loop identical to the round-5 kernel (measured 683 TF effective).
// EPI selects a fused epilogue:
//   2 = NO C store; in-register softmax over d (64 rows of this wave = one
//       head, cross-lane over h via shfl_xor 16/32), *SCALE, split-bf16,
//       transposed store p^T[b][n][c] -> P0/P1          (q projection)
//   3 = bias + C store + per-column sum-of-squares partial
//       -> S0[(by*2+wr)][b][n]                          (output projection)
//   4 = merged K|V (M=1024, A = [Wk;Wv] concat): by<4 -> k slab: C store to
//       C(kbuf) + per-row softmax partials (max,sumexp) over this WAVE's
//       64 cols -> S0/S1[row*64 + bx*2 + wc] (distinct slot per wave —
//       two waves share rows but cover different col-halves);
//       by>=4 -> v slab: plain store to C2(vbuf) at row-512.
// ---------------------------------------------------------------------------
template<int EPI>
__global__ __launch_bounds__(256)
void gemm_split(const u16* __restrict__ Ahi, const u16* __restrict__ Alo,
                const u16* __restrict__ Bhi, const u16* __restrict__ Blo,
                float* __restrict__ C, float* __restrict__ C2,
                const float* __restrict__ bias,
                u16* __restrict__ P0, u16* __restrict__ P1,
                float* __restrict__ S0, float* __restrict__ S1,
                int N, int K,
                long long sA, long long sB, long long sC)
{
    Ahi += (long long)blockIdx.z * sA; Alo += (long long)blockIdx.z * sA;
    Bhi += (long long)blockIdx.z * sB; Blo += (long long)blockIdx.z * sB;
    C   += (long long)blockIdx.z * sC;
    if (EPI == 4) C2 += (long long)blockIdx.z * sC;

    __shared__ __align__(16) char sb[32768];   // A 16KB | B 16KB

    const int tid = threadIdx.x;
    const int w = tid >> 6, lane = tid & 63;
    const int wr = w >> 1, wc = w & 1;
    const int row0 = blockIdx.y * 128, col0 = blockIdx.x * 128;

    // staging: lane writes LDS slot (lane&7) of row (lane>>3) in its chunk
    // (linear, HW-imposed); it must therefore LOAD global octet (slot^row).
    const int rsub = lane >> 3;              // row within an 8-row chunk
    const int jsel = (lane & 7) ^ rsub;      // global octet id (0-3 hi, 4-7 lo)
    const int koff = (jsel & 3) << 3;        // k offset in elements
    const u16* aops = (jsel < 4) ? Ahi : Alo;
    const u16* bops = (jsel < 4) ? Bhi : Blo;

    // fragment read offsets (constant across k-steps)
    const int r = lane & 15, h = lane >> 4;
    const int s_hi = (h ^ (r & 7)) << 4;
    const int s_lo = ((h + 4) ^ (r & 7)) << 4;
    int offA[4][2], offB[4][2];
#pragma unroll
    for (int i = 0; i < 4; ++i) {
        const int ra = (wr * 64 + i * 16 + r) * 128;
        offA[i][0] = ra + s_hi;  offA[i][1] = ra + s_lo;
        const int rb = 16384 + (wc * 64 + i * 16 + r) * 128;
        offB[i][0] = rb + s_hi;  offB[i][1] = rb + s_lo;
    }

    f32x4 acc[4][4];
#pragma unroll
    for (int i = 0; i < 4; ++i)
#pragma unroll
        for (int j = 0; j < 4; ++j) acc[i][j] = (f32x4){0.f, 0.f, 0.f, 0.f};

    for (int k0 = 0; k0 < K; k0 += 32) {
        __syncthreads();   // previous tile's reads complete before overwrite
#pragma unroll
        for (int i = 0; i < 4; ++i) {
            const int t = 4 * w + i;   // 8-row chunk index, 0..15
            gload_lds16(aops + (long long)(row0 + 8 * t + rsub) * K + k0 + koff,
                        sb + t * 1024);
            gload_lds16(bops + (long long)(col0 + 8 * t + rsub) * K + k0 + koff,
                        sb + 16384 + t * 1024);
        }
        __syncthreads();   // drains vmcnt: staged data visible

        bf16x8 ah[4], al[4], bh[4], bl[4];
#pragma unroll
        for (int i = 0; i < 4; ++i) {
            ah[i] = *(const bf16x8*)(sb + offA[i][0]);
            al[i] = *(const bf16x8*)(sb + offA[i][1]);
            bh[i] = *(const bf16x8*)(sb + offB[i][0]);
            bl[i] = *(const bf16x8*)(sb + offB[i][1]);
        }
#pragma unroll
        for (int mi = 0; mi < 4; ++mi)
#pragma unroll
            for (int ni = 0; ni < 4; ++ni) {
                acc[mi][ni] = __builtin_amdgcn_mfma_f32_16x16x32_bf16(ah[mi], bh[ni], acc[mi][ni], 0, 0, 0);
                acc[mi][ni] = __builtin_amdgcn_mfma_f32_16x16x32_bf16(ah[mi], bl[ni], acc[mi][ni], 0, 0, 0);
                acc[mi][ni] = __builtin_amdgcn_mfma_f32_16x16x32_bf16(al[mi], bh[ni], acc[mi][ni], 0, 0, 0);
            }
    }

    // --- epilogues. C/D layout: col=lane&15(r), row=(lane>>4)*4+reg [m89] ---
    const int bx = blockIdx.x, by = blockIdx.y, bz = blockIdx.z;

    if constexpr (EPI == 2) {
        // softmax over d per column n: the wave's 64 rows are exactly one
        // head (by*2+wr). Column fixed <=> (ni, r) fixed; rows live on the 4
        // h-lanes (16 values each). shfl_xor 16/32 flips h-bits only.
#pragma unroll
        for (int ni = 0; ni < 4; ++ni) {
            float cm = -INFINITY;
#pragma unroll
            for (int mi = 0; mi < 4; ++mi)
#pragma unroll
                for (int reg = 0; reg < 4; ++reg)
                    cm = fmaxf(cm, acc[mi][ni][reg]);
            cm = fmaxf(cm, __shfl_xor(cm, 16));
            cm = fmaxf(cm, __shfl_xor(cm, 32));
            float cs = 0.f;
#pragma unroll
            for (int mi = 0; mi < 4; ++mi)
#pragma unroll
                for (int reg = 0; reg < 4; ++reg) {
                    const float e = __expf(acc[mi][ni][reg] - cm);
                    acc[mi][ni][reg] = e;
                    cs += e;
                }
            cs += __shfl_xor(cs, 16);
            cs += __shfl_xor(cs, 32);
            const float inv = SCALE_Q / cs;
            const long long coln = col0 + wc * 64 + ni * 16 + r;
            const long long obase = ((long long)bz * NSEQ + coln) * CDIM
                                    + row0 + wr * 64 + h * 4;
#pragma unroll
            for (int mi = 0; mi < 4; ++mi) {
                u16 hv0, lv0, hv1, lv1, hv2, lv2, hv3, lv3;
                split_bf(acc[mi][ni][0] * inv, hv0, lv0);
                split_bf(acc[mi][ni][1] * inv, hv1, lv1);
                split_bf(acc[mi][ni][2] * inv, hv2, lv2);
                split_bf(acc[mi][ni][3] * inv, hv3, lv3);
                ushort4 hq; hq.x = hv0; hq.y = hv1; hq.z = hv2; hq.w = hv3;
                ushort4 lq; lq.x = lv0; lq.y = lv1; lq.z = lv2; lq.w = lv3;
                *(ushort4*)&P0[obase + mi * 16] = hq;   // 8B aligned
                *(ushort4*)&P1[obase + mi * 16] = lq;
            }
        }
        return;
    }

    if constexpr (EPI == 4) {
        const bool isK = (by < 4);
        float* Cd = isK ? C : C2;
        const int rbase = isK ? row0 : row0 - 512;
#pragma unroll
        for (int mi = 0; mi < 4; ++mi) {
            const int rowm = rbase + wr * 64 + mi * 16 + h * 4;
#pragma unroll
            for (int ni = 0; ni < 4; ++ni) {
                const int coln = col0 + wc * 64 + ni * 16 + r;
#pragma unroll
                for (int reg = 0; reg < 4; ++reg)
                    Cd[(long long)(rowm + reg) * N + coln] = acc[mi][ni][reg];
            }
        }
        if (isK) {
            // per-row max & sumexp partials over THIS WAVE's 64 cols
#pragma unroll
            for (int mi = 0; mi < 4; ++mi)
#pragma unroll
                for (int reg = 0; reg < 4; ++reg) {
                    float m = -INFINITY;
#pragma unroll
                    for (int ni = 0; ni < 4; ++ni) m = fmaxf(m, acc[mi][ni][reg]);
                    m = fmaxf(m, __shfl_xor(m, 1));
                    m = fmaxf(m, __shfl_xor(m, 2));
                    m = fmaxf(m, __shfl_xor(m, 4));
                    m = fmaxf(m, __shfl_xor(m, 8));
                    float s = 0.f;
#pragma unroll
                    for (int ni = 0; ni < 4; ++ni) s += __expf(acc[mi][ni][reg] - m);
                    s += __shfl_xor(s, 1);
                    s += __shfl_xor(s, 2);
                    s += __shfl_xor(s, 4);
                    s += __shfl_xor(s, 8);
                    if (r == 0) {
                        const int srow = bz * CDIM + row0 + wr * 64 + mi * 16 + h * 4 + reg;
                        S0[srow * 64 + bx * 2 + wc] = m;
                        S1[srow * 64 + bx * 2 + wc] = s;
                    }
                }
        }
        return;
    }

    if constexpr (EPI == 3) {
        // pre-add bias so the ss-partials see final values
#pragma unroll
        for (int mi = 0; mi < 4; ++mi) {
            const int rowm = row0 + wr * 64 + mi * 16 + h * 4;
#pragma unroll
            for (int reg = 0; reg < 4; ++reg) {
                const float bv = bias[rowm + reg];
#pragma unroll
                for (int ni = 0; ni < 4; ++ni) acc[mi][ni][reg] += bv;
            }
        }
        // C store
#pragma unroll
        for (int mi = 0; mi < 4; ++mi) {
            const int rowm = row0 + wr * 64 + mi * 16 + h * 4;
#pragma unroll
            for (int ni = 0; ni < 4; ++ni) {
                const int coln = col0 + wc * 64 + ni * 16 + r;
#pragma unroll
                for (int reg = 0; reg < 4; ++reg)
                    C[(long long)(rowm + reg) * N + coln] = acc[mi][ni][reg];
            }
        }
        // per-column sum-of-squares partial over this block's 128 rows
        // (each column written by exactly one wave: wc splits columns)
#pragma unroll
        for (int ni = 0; ni < 4; ++ni) {
            float ss = 0.f;
#pragma unroll
            for (int mi = 0; mi < 4; ++mi)
#pragma unroll
                for (int reg = 0; reg < 4; ++reg)
                    ss += acc[mi][ni][reg] * acc[mi][ni][reg];
            ss += __shfl_xor(ss, 16);
            ss += __shfl_xor(ss, 32);
            if (h == 0) {
                const int coln = col0 + wc * 64 + ni * 16 + r;
                S0[(long long)(by * 2 + wr) * (NB * NSEQ)
                   + (long long)bz * NSEQ + coln] = ss;
            }
        }
    }
}

// ---------------------------------------------------------------------------
// k-stats finalize: combine 64 per-wave partials per row.
// sum(exp(x - m)) = sum_i psum_i * exp(pmax_i - m)
// ---------------------------------------------------------------------------
__global__ __launch_bounds__(256)
void kfin_kernel(const float* __restrict__ pmax, const float* __restrict__ psum,
                 float* __restrict__ kmax, float* __restrict__ kinv)
{
    const int row = blockIdx.x * 256 + threadIdx.x;   // grid 16 -> 4096
    float m = -INFINITY;
#pragma unroll
    for (int i = 0; i < 64; ++i) m = fmaxf(m, pmax[row * 64 + i]);
    float s = 0.f;
#pragma unroll
    for (int i = 0; i < 64; ++i)
        s += psum[row * 64 + i] * __expf(pmax[row * 64 + i] - m);
    kmax[row] = m;
    kinv[row] = 1.0f / s;
}

// ---------------------------------------------------------------------------
// Weight split (Wq|Wk|Wv selected by blockIdx.y): fp32 -> (hi, lo) bf16.
// ---------------------------------------------------------------------------
__global__ __launch_bounds__(256)
void cvt3(const float* __restrict__ Wq, const float* __restrict__ Wk,
          const float* __restrict__ Wv, u16* __restrict__ hi,
          u16* __restrict__ lo)
{
    const float* src = (blockIdx.y == 0) ? Wq : ((blockIdx.y == 1) ? Wk : Wv);
    u16* hd = hi + (long long)blockIdx.y * 262144;
    u16* ld = lo + (long long)blockIdx.y * 262144;
    for (int i = blockIdx.x * 256 + threadIdx.x; i < 262144; i += 16384) {
        u16 h, l; split_bf(src[i], h, l);
        hd[i] = h; ld[i] = l;
    }
}

// ---------------------------------------------------------------------------
// x [b][c][n] fp32 -> xT hi/lo bf16 [b][n][c]  (LDS 64x64 tile transpose)
// ---------------------------------------------------------------------------
__global__ __launch_bounds__(256)
void xpose_split(const float* __restrict__ x, u16* __restrict__ thi,
                 u16* __restrict__ tlo)
{
    __shared__ float t[64][65];
    const int tid = threadIdx.x;
    const int b = blockIdx.z, c0 = blockIdx.y * 64, n0 = blockIdx.x * 64;
    const float* xb = x + ((long long)b * CDIM + c0) * NSEQ + n0;
#pragma unroll
    for (int i = 0; i < 16; ++i) {
        const int f = tid + i * 256;
        t[f >> 6][f & 63] = xb[(long long)(f >> 6) * NSEQ + (f & 63)];
    }
    __syncthreads();
#pragma unroll
    for (int i = 0; i < 8; ++i) {
        const int f = tid + i * 256;
        const int nl = f >> 5, c2 = (f & 31) << 1;
        u16 h0, l0, h1, l1;
        split_bf(t[c2][nl], h0, l0);
        split_bf(t[c2 + 1][nl], h1, l1);
        const long long o = ((long long)b * NSEQ + n0 + nl) * CDIM + c0 + c2;
        ushort2 hv; hv.x = h0; hv.y = h1; *(ushort2*)&thi[o] = hv;
        ushort2 lv; lv.x = l0; lv.y = l1; *(ushort2*)&tlo[o] = lv;
    }
}

// ---------------------------------------------------------------------------
// ctx_part[chunk][b,h,d,e] = sum over 512-col n-chunk of
//   softmax_n(k)[d,n] * v[e,n].   No atomics; reduced by ctx_reduce.
// ---------------------------------------------------------------------------
__global__ __launch_bounds__(256)
void ctx_part_kernel(const float* __restrict__ k, const float* __restrict__ v,
                     const float* __restrict__ kmax, const float* __restrict__ kinv,
                     float* __restrict__ ctx_part)
{
    const int chunk = blockIdx.x;        // 0..7
    const int bh = blockIdx.y;           // 0..63
    const int b = bh >> 3, h = bh & 7;

    __shared__ float kt[64 * 64];
    __shared__ float vt[64 * 64];

    const int tid = threadIdx.x;
    const int td = tid & 15, te = tid >> 4;
    const long long rowbase = (long long)b * CDIM + h * DHEAD;

    float acc[4][4];
#pragma unroll
    for (int i = 0; i < 4; ++i)
#pragma unroll
        for (int j = 0; j < 4; ++j) acc[i][j] = 0.f;

    for (int tile = 0; tile < 8; ++tile) {
        const int n0 = chunk * 512 + tile * 64;
        __syncthreads();
#pragma unroll
        for (int i = 0; i < 4; ++i) {
            const int f = tid + i * 256;
            const int row = f >> 4;
            const int c4 = (f & 15) << 2;
            const int cs = c4 ^ (((row >> 2) & 7) << 2);
            float4 kv = *(const float4*)&k[(rowbase + row) * (long long)NSEQ + n0 + c4];
            const float m_ = kmax[rowbase + row];
            const float s_ = kinv[rowbase + row];
            kv.x = __expf(kv.x - m_) * s_; kv.y = __expf(kv.y - m_) * s_;
            kv.z = __expf(kv.z - m_) * s_; kv.w = __expf(kv.w - m_) * s_;
            *(float4*)&kt[row * 64 + cs] = kv;
            *(float4*)&vt[row * 64 + cs] =
                *(const float4*)&v[(rowbase + row) * (long long)NSEQ + n0 + c4];
        }
        __syncthreads();

#pragma unroll
        for (int nn = 0; nn < 64; nn += 4) {
            float4 ka[4], vb[4];
#pragma unroll
            for (int i = 0; i < 4; ++i) {
                const int d = td * 4 + i;
                ka[i] = *(const float4*)&kt[d * 64 + (nn ^ (((d >> 2) & 7) << 2))];
            }
#pragma unroll
            for (int j = 0; j < 4; ++j) {
                const int e = te * 4 + j;
                vb[j] = *(const float4*)&vt[e * 64 + (nn ^ (((e >> 2) & 7) << 2))];
            }
#pragma unroll
            for (int i = 0; i < 4; ++i)
#pragma unroll
                for (int j = 0; j < 4; ++j) {
                    acc[i][j] = fmaf(ka[i].x, vb[j].x, acc[i][j]);
                    acc[i][j] = fmaf(ka[i].y, vb[j].y, acc[i][j]);
                    acc[i][j] = fmaf(ka[i].z, vb[j].z, acc[i][j]);
                    acc[i][j] = fmaf(ka[i].w, vb[j].w, acc[i][j]);
                }
        }
    }

    float* cbase = ctx_part + (long long)chunk * 262144 + ((long long)bh << 12);
#pragma unroll
    for (int i = 0; i < 4; ++i)
#pragma unroll
        for (int j = 0; j < 4; ++j)
            cbase[(td * 4 + i) * 64 + te * 4 + j] = acc[i][j];
}

__global__ __launch_bounds__(256)
void ctx_reduce(const float* __restrict__ part, float* __restrict__ ctx)
{
    const int i = blockIdx.x * 256 + threadIdx.x;   // grid 1024 -> 262144
    float s = 0.f;
#pragma unroll
    for (int c = 0; c < 8; ++c) s += part[(long long)c * 262144 + i];
    ctx[i] = s;
}

// ---------------------------------------------------------------------------
// W2[b][o][h*64+d] = sum_e Wout[o][h*64+e] * ctx[b][h][d][e] -> split bf16
// ---------------------------------------------------------------------------
__global__ __launch_bounds__(256)
void w2_split(const float* __restrict__ Wout, const float* __restrict__ ctx,
              u16* __restrict__ w2hi, u16* __restrict__ w2lo)
{
    const int o0 = blockIdx.x * 128;
    const int h = blockIdx.y, b = blockIdx.z;
    const int tid = threadIdx.x;

    __shared__ float ctxT[64 * 65];      // [e][d]
    __shared__ float WoutS[128 * 65];    // [o_local][e]

    const float* csrc = ctx + (((long long)b * NHEAD + h) << 12);
#pragma unroll
    for (int i = 0; i < 16; ++i) {
        const int f = tid + i * 256;
        ctxT[(f & 63) * 65 + (f >> 6)] = csrc[f];
    }
#pragma unroll
    for (int i = 0; i < 32; ++i) {
        const int f = tid + i * 256;
        WoutS[(f >> 6) * 65 + (f & 63)] =
            Wout[(long long)(o0 + (f >> 6)) * CDIM + h * DHEAD + (f & 63)];
    }
    __syncthreads();

    const int d = tid & 63, og = tid >> 6;
    float acc[32];
#pragma unroll
    for (int oo = 0; oo < 32; ++oo) acc[oo] = 0.f;

    for (int e = 0; e < 64; ++e) {
        const float c = ctxT[e * 65 + d];
#pragma unroll
        for (int oo = 0; oo < 32; ++oo)
            acc[oo] = fmaf(WoutS[(og * 32 + oo) * 65 + e], c, acc[oo]);
    }
#pragma unroll
    for (int oo = 0; oo < 32; ++oo) {
        const int o = o0 + og * 32 + oo;
        u16 hh, ll; split_bf(acc[oo], hh, ll);
        const long long idx = ((long long)b * CDIM + o) * CDIM + h * DHEAD + d;
        w2hi[idx] = hh; w2lo[idx] = ll;
    }
}

// ---------------------------------------------------------------------------
// RMSNorm pass 2 (FIXED): grid (64, NB) = 512 blocks. Thread handles one
// column n (64 coalesced per block); 4 thread-groups cover 128 channels
// each. Single outpre read; rn from the final-GEMM ss-partials.
// Round-7 version used 32 blocks (0.125/CU) -> 141 us latency-bound.
// ---------------------------------------------------------------------------
__global__ __launch_bounds__(256)
void rmsnorm2(const float* __restrict__ pre, const float* __restrict__ ssp,
              const float* __restrict__ g, float* __restrict__ out)
{
    const int tid = threadIdx.x;
    const int b = blockIdx.y;
    const int n = blockIdx.x * 64 + (tid & 63);
    const int cg = tid >> 6;

    float ss = 0.f;
#pragma unroll
    for (int p = 0; p < 8; ++p)
        ss += ssp[((long long)p * NB + b) * NSEQ + n];
    const float rn = SQRT_C / fmaxf(sqrtf(ss), 1e-12f);

    const float* pb = pre + (long long)b * CDIM * NSEQ + n;
    float* ob = out + (long long)b * CDIM * NSEQ + n;
#pragma unroll 4
    for (int c = cg * 128; c < cg * 128 + 128; ++c)
        ob[(long long)c * NSEQ] = pb[(long long)c * NSEQ] * rn * g[c];
}

// ---------------------------------------------------------------------------
// Workspace layout (floats), lifetime-packed, unchanged total (~155 MB):
//   region A [0, QK)      : xT split (2xQK u16)
//   region B [QK, 2QK)    : k -> out_pre (serial reuse)
//   region C [2QK, ...)   : kmax | kinv | ctx | ctxp (overlaid in time by
//                           {pmax,psum} then ctx_part then ssp) | W | W2
//   d_out                 : v -> p^T split -> final output (serial reuse)
// ---------------------------------------------------------------------------
extern "C" void kernel_launch(void* const* d_in, const int* in_sizes, int n_in,
                              void* d_out, int out_size, void* d_ws, size_t ws_size,
                              hipStream_t stream)
{
    const float* x    = (const float*)d_in[0];
    const float* Wq   = (const float*)d_in[1];
    const float* Wk   = (const float*)d_in[2];
    const float* Wv   = (const float*)d_in[3];
    const float* Wout = (const float*)d_in[4];
    const float* bout = (const float*)d_in[5];
    const float* g    = (const float*)d_in[6];
    float* out = (float*)d_out;

    const long long PB = (long long)CDIM * NSEQ;     // 2,097,152
    const long long QK = (long long)NB * PB;         // 16,777,216

    const long long C_FLOATS = 8192 + 9LL * 262144 + 11LL * 262144;
    const size_t WS_NEEDED = (size_t)(2 * QK + C_FLOATS) * sizeof(float);
    if (ws_size < WS_NEEDED) return;   // constant across calls: capture-safe

    float* ws = (float*)d_ws;
    u16* xthi = (u16*)ws;                  // region A: QK u16
    u16* xtlo = xthi + QK;                 //           QK u16
    float* buf1 = ws + QK;                 // region B: QK floats
    float* kmax = ws + 2 * QK;             // region C
    float* kinv = kmax + 4096;
    float* ctx  = kinv + 4096;             // 262144
    float* ctxp = ctx + 262144;            // 8 x 262144 (time-shared)
    u16* whi    = (u16*)(ctxp + 8 * 262144);   // 3 x 262144 u16
    u16* wlo    = whi + 3 * 262144;
    u16* w2hi   = wlo + 3 * 262144;        // 8 x 262144 u16
    u16* w2lo   = w2hi + (long long)NB * 262144;

    // time-shared overlays of ctxp (disjoint lifetimes):
    float* pmax = ctxp;                    // 262144   (kvGEMM -> kfin)
    float* psum = ctxp + 262144;           // 262144
    float* ssp  = ctxp;                    // 262144   (fGEMM -> rmsnorm2)

    float* kbuf = buf1;                    // k until ctx done
    float* outpre = buf1;                  // then final GEMM output
    float* vbuf = out;                     // d_out: v until ctx done
    u16* phi = (u16*)out;                  // then p^T split (2xQK u16 = QK f32)
    u16* plo = phi + QK;

    // weight + input splits
    cvt3<<<dim3(64, 3), 256, 0, stream>>>(Wq, Wk, Wv, whi, wlo);
    xpose_split<<<dim3(64, 8, 8), 256, 0, stream>>>(x, xthi, xtlo);

    // merged K|V projection (A = [Wk;Wv] contiguous in whi/wlo at +262144),
    // fused k softmax-stat partials
    gemm_split<4><<<dim3(32, 8, 8), 256, 0, stream>>>(
        whi + 262144, wlo + 262144, xthi, xtlo,
        kbuf, vbuf, nullptr, nullptr, nullptr, pmax, psum,
        NSEQ, CDIM, 0, PB, PB);
    kfin_kernel<<<dim3(16), 256, 0, stream>>>(pmax, psum, kmax, kinv);

    // context accumulation
    ctx_part_kernel<<<dim3(8, NB * NHEAD), 256, 0, stream>>>(kbuf, vbuf, kmax, kinv, ctxp);
    ctx_reduce<<<1024, 256, 0, stream>>>(ctxp, ctx);

    // q projection with fused softmax -> p^T (written into d_out; v is dead)
    gemm_split<2><<<dim3(32, 4, 8), 256, 0, stream>>>(
        whi, wlo, xthi, xtlo,
        buf1, nullptr, nullptr, phi, plo, nullptr, nullptr,
        NSEQ, CDIM, 0, PB, PB);

    // fold ctx into output weights, output projection + bias + ss-partials
    w2_split<<<dim3(4, NHEAD, NB), 256, 0, stream>>>(Wout, ctx, w2hi, w2lo);
    gemm_split<3><<<dim3(32, 4, 8), 256, 0, stream>>>(
        w2hi, w2lo, phi, plo,
        outpre, nullptr, bout, nullptr, nullptr, ssp, nullptr,
        NSEQ, CDIM, 262144, PB, PB);

    // RMSNorm epilogue (single outpre read, properly parallel)
    rmsnorm2<<<dim3(64, NB), 256, 0, stream>>>(outpre, ssp, g, out);
}